// Round 9
// baseline (247.610 us; speedup 1.0000x reference)
//
#include <hip/hip_runtime.h>
#include <hip/hip_bf16.h>
#include <math.h>

#define NNODES 10000
#define NEDGES 80000
#define FDIM   1024
#define BGR    32
#define LLEN   800
#define CCH    16
#define DDIM   128
#define NPAD   10112   // 79 * 128

typedef __attribute__((ext_vector_type(4))) _Float16 f16x4;
typedef __attribute__((ext_vector_type(8))) _Float16 f16x8;
typedef __attribute__((ext_vector_type(4))) float f32x4;

__device__ __forceinline__ float lrelu(float v){ return v > 0.0f ? v : 0.01f*v; }

// zero cnt + cursor for both branches
__global__ __launch_bounds__(256) void k_initcnt(int* cnt, int* cursor){
  int n = blockIdx.x*256 + threadIdx.x;
  if (n < 2*NNODES){ cnt[n] = 0; cursor[n] = 0; }
}

__global__ __launch_bounds__(256) void k_edgedeg(const int* __restrict__ ei0,
                                                 const int* __restrict__ ei1, int* cnt){
  int i = blockIdx.x*256 + threadIdx.x;
  if (i >= 2*NEDGES) return;
  int br = i >= NEDGES;
  int e  = br ? i - NEDGES : i;
  const int* ei = br ? ei1 : ei0;
  atomicAdd(&cnt[br*NNODES + ei[NEDGES + e]], 1);
}

// per-branch exclusive scan + dinv + batch-range bstart; grid=2 blocks of 1024
__global__ __launch_bounds__(1024) void k_scan(const int* __restrict__ cnt, int* __restrict__ rowstart,
                                               float* __restrict__ dinv,
                                               const int* __restrict__ batch0,
                                               const int* __restrict__ batch1,
                                               int* __restrict__ bstart_){
  __shared__ int part[1024];
  const int br = blockIdx.x;
  const int* c = cnt + br*NNODES;
  int* rs = rowstart + br*(NNODES+1);
  float* dv = dinv + br*NNODES;
  const int* batch = br ? batch1 : batch0;
  int* bstart = bstart_ + br*(BGR+1);
  const int t = threadIdx.x;
  const int base = t*10;
  int local[10];
  int s = 0;
  #pragma unroll
  for (int i = 0; i < 10; ++i){
    int v = (base+i < NNODES) ? c[base+i] : 0;
    local[i] = s; s += v;
    if (base+i < NNODES) dv[base+i] = rsqrtf((float)v + 1.0f);
  }
  part[t] = s;
  __syncthreads();
  for (int off = 1; off < 1024; off <<= 1){
    int v = (t >= off) ? part[t-off] : 0;
    __syncthreads();
    part[t] += v;
    __syncthreads();
  }
  const int prev = (t == 0) ? 0 : part[t-1];
  #pragma unroll
  for (int i = 0; i < 10; ++i)
    if (base+i < NNODES) rs[base+i] = prev + local[i];
  if (t == 0) rs[NNODES] = NEDGES;
  for (int i = base; i < base+10 && i < NNODES; ++i){
    int b = batch[i];
    if (i == 0){ for (int bb = 0; bb <= b; ++bb) bstart[bb] = 0; }
    else {
      int pb = batch[i-1];
      if (b != pb) for (int bb = pb+1; bb <= b; ++bb) bstart[bb] = i;
    }
    if (i == NNODES-1){ for (int bb = b+1; bb <= BGR; ++bb) bstart[bb] = NNODES; }
  }
}

__global__ __launch_bounds__(256) void k_fill(const int* __restrict__ ei0,
                                              const int* __restrict__ ei1,
                                              const int* __restrict__ rowstart,
                                              int* __restrict__ cursor,
                                              int* __restrict__ csr){
  int i = blockIdx.x*256 + threadIdx.x;
  if (i >= 2*NEDGES) return;
  int br = i >= NEDGES;
  int e  = br ? i - NEDGES : i;
  const int* ei = br ? ei1 : ei0;
  int r = ei[e], c = ei[NEDGES + e];
  int pos = atomicAdd(&cursor[br*NNODES + c], 1);
  csr[br*NEDGES + rowstart[br*(NNODES+1) + c] + pos] = r;
}

// fused: blocks [0,NNODES) do xs[r]=dinv[r]*x[r] (f32->f16);
// blocks [NNODES, NNODES+1024) do the LDS-tiled W transpose+cast. grid (NNODES+1024, 2)
__global__ __launch_bounds__(256) void k_cvtXW(const float* __restrict__ x0,
                                               const float* __restrict__ x1,
                                               const float* __restrict__ dinv,
                                               _Float16* __restrict__ xs,
                                               const float* __restrict__ W0,
                                               const float* __restrict__ W1,
                                               _Float16* __restrict__ Wt){
  const int br = blockIdx.y;
  const int bx = blockIdx.x;
  const int t = threadIdx.x;
  if (bx < NNODES){
    const int row = bx;
    const float* x = (br ? x1 : x0) + (size_t)row*FDIM;
    _Float16* o = xs + ((size_t)br*NNODES + row)*FDIM;
    const int f = t*4;
    const float d = dinv[br*NNODES + row];
    const float4 v = *(const float4*)(x + f);
    f16x4 ov;
    ov[0]=(_Float16)(v.x*d); ov[1]=(_Float16)(v.y*d); ov[2]=(_Float16)(v.z*d); ov[3]=(_Float16)(v.w*d);
    *(f16x4*)(o + f) = ov;
  } else {
    const int tile = bx - NNODES;           // 0..1023
    const float* W = br ? W1 : W0;
    _Float16* Wo = Wt + (size_t)br*FDIM*FDIM;
    __shared__ float tl[32][33];
    const int k0 = (tile >> 5)*32, n0 = (tile & 31)*32;
    const int r = t >> 3, c4 = (t & 7)*4;
    const float4 v = *(const float4*)(W + (size_t)(k0+r)*FDIM + n0 + c4);
    tl[r][c4] = v.x; tl[r][c4+1] = v.y; tl[r][c4+2] = v.z; tl[r][c4+3] = v.w;
    __syncthreads();
    f16x4 o;
    o[0]=(_Float16)tl[c4  ][r];
    o[1]=(_Float16)tl[c4+1][r];
    o[2]=(_Float16)tl[c4+2][r];
    o[3]=(_Float16)tl[c4+3][r];
    *(f16x4*)(Wo + (size_t)(n0+r)*FDIM + k0 + c4) = o;
  }
}

// xa[c] = dinv[c]*(xs[c] + sum_{r->c} xs[r]); grid (NPAD, 2), 128 thr
__global__ __launch_bounds__(128) void k_gather(const _Float16* __restrict__ xs_,
                                                const int* __restrict__ rowstart_,
                                                const int* __restrict__ csr_,
                                                const float* __restrict__ dinv_,
                                                _Float16* __restrict__ xa_){
  const int br = blockIdx.y;
  const _Float16* xs = xs_ + (size_t)br*NNODES*FDIM;
  const int* rowstart = rowstart_ + br*(NNODES+1);
  const int* csr = csr_ + br*NEDGES;
  const float* dinv = dinv_ + br*NNODES;
  _Float16* xa = xa_ + (size_t)br*NPAD*FDIM;

  const int n = blockIdx.x;
  const int f = threadIdx.x*8;
  _Float16* op = xa + (size_t)n*FDIM + f;
  if (n >= NNODES){
    f16x8 z = {};
    *(f16x8*)op = z;
    return;
  }
  const int s0 = rowstart[n], s1 = rowstart[n+1];
  f16x8 sv = *(const f16x8*)(xs + (size_t)n*FDIM + f);
  float a0=sv[0],a1=sv[1],a2=sv[2],a3=sv[3],a4=sv[4],a5=sv[5],a6=sv[6],a7=sv[7];
  int i = s0;
  for (; i + 4 <= s1; i += 4){
    const int r0 = csr[i], r1 = csr[i+1], r2 = csr[i+2], r3 = csr[i+3];
    f16x8 v0 = *(const f16x8*)(xs + (size_t)r0*FDIM + f);
    f16x8 v1 = *(const f16x8*)(xs + (size_t)r1*FDIM + f);
    f16x8 v2 = *(const f16x8*)(xs + (size_t)r2*FDIM + f);
    f16x8 v3 = *(const f16x8*)(xs + (size_t)r3*FDIM + f);
    a0 += (float)v0[0]+(float)v1[0]+(float)v2[0]+(float)v3[0];
    a1 += (float)v0[1]+(float)v1[1]+(float)v2[1]+(float)v3[1];
    a2 += (float)v0[2]+(float)v1[2]+(float)v2[2]+(float)v3[2];
    a3 += (float)v0[3]+(float)v1[3]+(float)v2[3]+(float)v3[3];
    a4 += (float)v0[4]+(float)v1[4]+(float)v2[4]+(float)v3[4];
    a5 += (float)v0[5]+(float)v1[5]+(float)v2[5]+(float)v3[5];
    a6 += (float)v0[6]+(float)v1[6]+(float)v2[6]+(float)v3[6];
    a7 += (float)v0[7]+(float)v1[7]+(float)v2[7]+(float)v3[7];
  }
  for (; i < s1; ++i){
    const int r = csr[i];
    f16x8 v = *(const f16x8*)(xs + (size_t)r*FDIM + f);
    a0+=(float)v[0]; a1+=(float)v[1]; a2+=(float)v[2]; a3+=(float)v[3];
    a4+=(float)v[4]; a5+=(float)v[5]; a6+=(float)v[6]; a7+=(float)v[7];
  }
  const float d = dinv[n];
  f16x8 o;
  o[0]=(_Float16)(a0*d); o[1]=(_Float16)(a1*d); o[2]=(_Float16)(a2*d); o[3]=(_Float16)(a3*d);
  o[4]=(_Float16)(a4*d); o[5]=(_Float16)(a5*d); o[6]=(_Float16)(a6*d); o[7]=(_Float16)(a7*d);
  *(f16x8*)op = o;
}

// hh = lrelu(xa @ W + b), f16 out; grid (79, 8, 2).
// XCD-local mapping + 3-buffer depth-2 counted-vmcnt pipeline, K-loop unrolled
// x3 so ALL buffer indices are compile-time (ds_read offsets become immediates;
// stage pointers strength-reduce). One barrier per K-step.
__global__ __launch_bounds__(256) void k_gemm(const _Float16* __restrict__ A_,
                                              const _Float16* __restrict__ Bt_,
                                              const float* __restrict__ bg0,
                                              const float* __restrict__ bg1,
                                              _Float16* __restrict__ hh_){
  const int id  = blockIdx.x + 79*(blockIdx.y + 8*blockIdx.z);  // 0..1263
  const int w   = (id & 7)*158 + (id >> 3);                     // XCD-local bijection
  const int col = w & 7;
  const int ru  = w >> 3;        // row-unit 0..157
  const int row = ru % 79;
  const int br  = ru / 79;

  const _Float16* A  = A_  + (size_t)br*NPAD*FDIM;
  const _Float16* Bt = Bt_ + (size_t)br*FDIM*FDIM;
  const float* bg = br ? bg1 : bg0;
  _Float16* hh = hh_ + (size_t)br*NPAD*FDIM;

  __shared__ _Float16 As[3][128*32];
  __shared__ _Float16 Bs[3][128*32];
  const int row0 = row*128, col0 = col*128;
  const int tid  = threadIdx.x;
  const int lane = tid & 63, wave = tid >> 6;
  const int wm = wave >> 1, wn = wave & 1;

  const int lr = lane >> 2;       // 0..15 row within 16-row group
  const int ls = lane & 3;        // linear 16B slot within row

  // loop-invariant staging bases (k advances via k0 argument only)
  const int ra0 = wave*32 + lr;           // rows this lane feeds (j=0)
  const int sa0 = ls ^ ((ra0 >> 1) & 3);
  const int ra1 = ra0 + 16;               // j=1
  const int sa1 = ls ^ ((ra1 >> 1) & 3);
  const _Float16* gA0 = A  + (size_t)(row0+ra0)*FDIM + sa0*8;
  const _Float16* gA1 = A  + (size_t)(row0+ra1)*FDIM + sa1*8;
  const _Float16* gB0 = Bt + (size_t)(col0+ra0)*FDIM + sa0*8;
  const _Float16* gB1 = Bt + (size_t)(col0+ra1)*FDIM + sa1*8;

  f32x4 acc[4][4] = {};

  auto stage = [&](int buf, int k0){
    const int r0 = wave*32;
    __builtin_amdgcn_global_load_lds(
      (const __attribute__((address_space(1))) void*)(gA0 + k0),
      (__attribute__((address_space(3))) void*)(&As[buf][r0*32]), 16, 0, 0);
    __builtin_amdgcn_global_load_lds(
      (const __attribute__((address_space(1))) void*)(gB0 + k0),
      (__attribute__((address_space(3))) void*)(&Bs[buf][r0*32]), 16, 0, 0);
    __builtin_amdgcn_global_load_lds(
      (const __attribute__((address_space(1))) void*)(gA1 + k0),
      (__attribute__((address_space(3))) void*)(&As[buf][(r0+16)*32]), 16, 0, 0);
    __builtin_amdgcn_global_load_lds(
      (const __attribute__((address_space(1))) void*)(gB1 + k0),
      (__attribute__((address_space(3))) void*)(&Bs[buf][(r0+16)*32]), 16, 0, 0);
  };

  auto compute = [&](int buf){
    f16x8 af[4], bf[4];
    const int s = lane >> 4;     // k-slot 0..3
    #pragma unroll
    for (int i = 0; i < 4; ++i){
      const int rA = wm*64 + i*16 + (lane&15);
      af[i] = *(const f16x8*)(&As[buf][rA*32 + (s ^ ((rA>>1)&3))*8]);
      const int rB = wn*64 + i*16 + (lane&15);
      bf[i] = *(const f16x8*)(&Bs[buf][rB*32 + (s ^ ((rB>>1)&3))*8]);
    }
    #pragma unroll
    for (int mi = 0; mi < 4; ++mi)
      #pragma unroll
      for (int ni = 0; ni < 4; ++ni)
        acc[mi][ni] = __builtin_amdgcn_mfma_f32_16x16x32_f16(af[mi], bf[ni], acc[mi][ni], 0, 0, 0);
  };

  // prologue: tiles 0,1 in flight
  stage(0, 0);
  stage(1, 32);
  asm volatile("s_waitcnt vmcnt(4)" ::: "memory");   // tile 0 landed
  __builtin_amdgcn_s_barrier();

  // main: 10 x 3 steps, compile-time buffers. Step ks: stage tile ks+2,
  // compute tile ks, vmcnt(4) (tile ks+1 landed), barrier.
  for (int kt = 0; kt < 10; ++kt){
    const int kb = kt*96;   // = 3*kt*32
    stage(2, kb + 64);  compute(0);
    asm volatile("s_waitcnt vmcnt(4)" ::: "memory");
    __builtin_amdgcn_s_barrier();
    stage(0, kb + 96);  compute(1);
    asm volatile("s_waitcnt vmcnt(4)" ::: "memory");
    __builtin_amdgcn_s_barrier();
    stage(1, kb + 128); compute(2);
    asm volatile("s_waitcnt vmcnt(4)" ::: "memory");
    __builtin_amdgcn_s_barrier();
  }
  // tail: tiles 30 (buf0, landed), 31 (buf1, in flight)
  compute(0);
  asm volatile("s_waitcnt vmcnt(0)" ::: "memory");
  __builtin_amdgcn_s_barrier();
  compute(1);

  float bcol[4];
  #pragma unroll
  for (int ni = 0; ni < 4; ++ni) bcol[ni] = bg[col0 + wn*64 + ni*16 + (lane & 15)];
  #pragma unroll
  for (int mi = 0; mi < 4; ++mi){
    #pragma unroll
    for (int j = 0; j < 4; ++j){
      const int grow = row0 + wm*64 + mi*16 + (lane>>4)*4 + j;
      _Float16* hr = hh + (size_t)grow*FDIM + col0 + wn*64 + (lane & 15);
      #pragma unroll
      for (int ni = 0; ni < 4; ++ni) hr[ni*16] = (_Float16)lrelu(acc[mi][ni][j] + bcol[ni]);
    }
  }
}

// pool[br][b][col] = mean over rows; grid (4, 32, 2), block 256
__global__ __launch_bounds__(256) void k_pool(const _Float16* __restrict__ hh_,
                                              const int* __restrict__ bstart_,
                                              float* __restrict__ pool_){
  const int br = blockIdx.z;
  const _Float16* hh = hh_ + (size_t)br*NPAD*FDIM;
  const int* bstart = bstart_ + br*(BGR+1);
  float* pool = pool_ + br*BGR*FDIM;
  const int b = blockIdx.y;
  const int col = blockIdx.x*256 + threadIdx.x;
  const int s0 = bstart[b], s1 = bstart[b+1];
  float sum = 0.f;
  int n = s0;
  for (; n + 4 <= s1; n += 4){
    float h0 = (float)hh[(size_t)(n  )*FDIM + col];
    float h1 = (float)hh[(size_t)(n+1)*FDIM + col];
    float h2 = (float)hh[(size_t)(n+2)*FDIM + col];
    float h3 = (float)hh[(size_t)(n+3)*FDIM + col];
    sum += (h0+h1)+(h2+h3);
  }
  for (; n < s1; ++n) sum += (float)hh[(size_t)n*FDIM + col];
  const float inv = 1.0f / fmaxf((float)(s1 - s0), 1.0f);
  pool[b*FDIM + col] = sum * inv;
}

// fused pf GEMV: x12[br][b][d] = lrelu(pool[b]·W[:,d] + bias[d]); grid (32,2), block 512
__global__ __launch_bounds__(512) void k_pf(const float* __restrict__ pool_,
                                            const float* __restrict__ W0,
                                            const float* __restrict__ W1,
                                            const float* __restrict__ bias0,
                                            const float* __restrict__ bias1,
                                            float* __restrict__ x12){
  __shared__ float red[512];
  const int br = blockIdx.y, b = blockIdx.x, t = threadIdx.x;
  const int d = t & 127, kq = t >> 7;          // 4 k-quarters
  const float* W = (br ? W1 : W0) + (size_t)kq*256*DDIM + d;
  const float* pp = pool_ + (size_t)(br*BGR + b)*FDIM + kq*256;
  float acc = 0.f;
  #pragma unroll 4
  for (int kk = 0; kk < 256; kk += 4){
    const float4 pv = *(const float4*)(pp + kk);
    acc += pv.x * W[(kk  )*DDIM] + pv.y * W[(kk+1)*DDIM]
         + pv.z * W[(kk+2)*DDIM] + pv.w * W[(kk+3)*DDIM];
  }
  red[t] = acc;
  __syncthreads();
  if (t < 128){
    float a = red[t] + red[t+128] + red[t+256] + red[t+384] + (br ? bias1 : bias0)[t];
    x12[((size_t)br*BGR + b)*DDIM + t] = lrelu(a);
  }
}

// masif both branches; grid (32,2)
__global__ __launch_bounds__(256) void k_masif(const float* __restrict__ ms1, const float* __restrict__ mf1,
                                               const float* __restrict__ ms2, const float* __restrict__ mf2,
                                               const float* __restrict__ sw1, const float* __restrict__ sb1,
                                               const float* __restrict__ fw1, const float* __restrict__ fb1,
                                               const float* __restrict__ sw2, const float* __restrict__ sb2,
                                               const float* __restrict__ fw2, const float* __restrict__ fb2,
                                               const float* __restrict__ Wm1, const float* __restrict__ bm1,
                                               const float* __restrict__ Wm2, const float* __restrict__ bm2,
                                               float* __restrict__ m12){
  __shared__ float sf[LLEN];
  __shared__ float w80[80];
  const int br = blockIdx.y, b = blockIdx.x, t = threadIdx.x;
  const float* ms = br ? ms2 : ms1;
  const float* mf = br ? mf2 : mf1;
  const float swv = (br ? sw2 : sw1)[0], sbv = (br ? sb2 : sb1)[0];
  const float fwv = (br ? fw2 : fw1)[0], fbv = (br ? fb2 : fb1)[0];
  const float* Wm = br ? Wm2 : Wm1;
  const float* bm = br ? bm2 : bm1;
  for (int l = t; l < LLEN; l += 256){
    float sm = 0.f, fm = 0.f;
    for (int c = 0; c < CCH; ++c){
      sm += ms[((size_t)b*CCH + c)*LLEN + l];
      fm += mf[((size_t)b*CCH + c)*LLEN + l];
    }
    sm = fmaxf(sm*(1.0f/16.0f)*swv + sbv, 0.f);
    fm = fmaxf(fm*(1.0f/16.0f)*fwv + fbv, 0.f);
    sf[l] = sm + fm;
  }
  __syncthreads();
  if (t < 80){
    float a = 0.f;
    for (int j = 0; j < 10; ++j) a += sf[t*10 + j];
    w80[t] = a * 0.05f;
  }
  __syncthreads();
  if (t < 64){
    float acc = bm[t];
    for (int k = 0; k < 80; ++k) acc += w80[k] * Wm[k*64 + t];
    m12[((size_t)br*BGR + b)*64 + t] = acc;
  }
}

// head: fc1 -> fc2 -> final sigmoid; grid 32, block 256
__global__ __launch_bounds__(256) void k_head(const float* __restrict__ x12,
                                              const float* __restrict__ Wfc1, const float* __restrict__ bfc1,
                                              const float* __restrict__ Wfc2, const float* __restrict__ bfc2,
                                              const float* __restrict__ m12,
                                              const float* __restrict__ Wout, const float* __restrict__ bout,
                                              float* __restrict__ out){
  __shared__ float xf[256];
  __shared__ float xc[64];
  __shared__ float red[192];
  const int b = blockIdx.x, t = threadIdx.x;
  const float* xin1 = x12 + (size_t)b*DDIM;
  const float* xin2 = x12 + (size_t)(BGR + b)*DDIM;
  float acc = bfc1[t];
  for (int k = 0; k < 128; ++k) acc += xin1[k] * Wfc1[k*256 + t];
  for (int k = 0; k < 128; ++k) acc += xin2[k] * Wfc1[(128+k)*256 + t];
  xf[t] = lrelu(acc);
  __syncthreads();
  if (t < 64){
    float a = bfc2[t];
    for (int k = 0; k < 256; ++k) a += xf[k] * Wfc2[k*64 + t];
    xc[t] = lrelu(a);
  }
  __syncthreads();
  if (t < 192){
    float v;
    if (t < 64)       v = xc[t] * Wout[t];
    else if (t < 128) v = m12[(size_t)b*64 + (t-64)] * Wout[t];
    else              v = m12[(size_t)(BGR + b)*64 + (t-128)] * Wout[t];
    red[t] = v;
  }
  __syncthreads();
  if (t == 0){
    float a = bout[0];
    for (int i = 0; i < 192; ++i) a += red[i];
    out[b] = 1.0f / (1.0f + expf(-a));
  }
}

extern "C" void kernel_launch(void* const* d_in, const int* in_sizes, int n_in,
                              void* d_out, int out_size, void* d_ws, size_t ws_size,
                              hipStream_t stream){
  const float* pro1_x = (const float*)d_in[0];
  const int*   ei1    = (const int*)d_in[1];
  const int*   batch1 = (const int*)d_in[2];
  const float* pro2_x = (const float*)d_in[3];
  const int*   ei2    = (const int*)d_in[4];
  const int*   batch2 = (const int*)d_in[5];
  const float* mas1_s = (const float*)d_in[6];
  const float* mas1_f = (const float*)d_in[7];
  const float* mas2_s = (const float*)d_in[8];
  const float* mas2_f = (const float*)d_in[9];
  const float* W_g1 = (const float*)d_in[10]; const float* b_g1 = (const float*)d_in[11];
  const float* W_g2 = (const float*)d_in[12]; const float* b_g2 = (const float*)d_in[13];
  const float* W_pf1= (const float*)d_in[14]; const float* b_pf1= (const float*)d_in[15];
  const float* W_pf2= (const float*)d_in[16]; const float* b_pf2= (const float*)d_in[17];
  const float* W_fc1= (const float*)d_in[18]; const float* b_fc1= (const float*)d_in[19];
  const float* W_fc2= (const float*)d_in[20]; const float* b_fc2= (const float*)d_in[21];
  const float* cs1w = (const float*)d_in[22]; const float* cs1b = (const float*)d_in[23];
  const float* cf1w = (const float*)d_in[24]; const float* cf1b = (const float*)d_in[25];
  const float* cs2w = (const float*)d_in[26]; const float* cs2b = (const float*)d_in[27];
  const float* cf2w = (const float*)d_in[28]; const float* cf2b = (const float*)d_in[29];
  const float* W_m1 = (const float*)d_in[30]; const float* b_m1 = (const float*)d_in[31];
  const float* W_m2 = (const float*)d_in[32]; const float* b_m2 = (const float*)d_in[33];
  const float* W_out= (const float*)d_in[34]; const float* b_out= (const float*)d_in[35];
  float* out = (float*)d_out;
  (void)in_sizes; (void)n_in; (void)out_size; (void)ws_size;

  char* p = (char*)d_ws;
  auto alloc = [&](size_t bytes)->char*{ char* r = p; p += (bytes + 255) & ~(size_t)255; return r; };
  _Float16* xs  = (_Float16*)alloc((size_t)2*NNODES*FDIM*2);
  _Float16* xa  = (_Float16*)alloc((size_t)2*NPAD*FDIM*2);
  _Float16* Wtb = (_Float16*)alloc((size_t)2*FDIM*FDIM*2);
  _Float16* hh  = (_Float16*)alloc((size_t)2*NPAD*FDIM*2);
  float* dinv = (float*)alloc((size_t)2*NNODES*4);
  int*   cnt  = (int*)alloc((size_t)2*NNODES*4);
  int*   cursor = (int*)alloc((size_t)2*NNODES*4);
  int*   rowstart = (int*)alloc((size_t)2*(NNODES+1)*4);
  int*   csr  = (int*)alloc((size_t)2*NEDGES*4);
  int*   bstart = (int*)alloc((size_t)2*(BGR+1)*4);
  float* pool = (float*)alloc((size_t)2*BGR*FDIM*4);
  float* x12  = (float*)alloc((size_t)2*BGR*DDIM*4);
  float* m12  = (float*)alloc((size_t)2*BGR*64*4);

  k_initcnt<<<(2*NNODES+255)/256, 256, 0, stream>>>(cnt, cursor);
  k_edgedeg<<<(2*NEDGES+255)/256, 256, 0, stream>>>(ei1, ei2, cnt);
  k_scan<<<2, 1024, 0, stream>>>(cnt, rowstart, dinv, batch1, batch2, bstart);
  k_fill<<<(2*NEDGES+255)/256, 256, 0, stream>>>(ei1, ei2, rowstart, cursor, csr);
  k_cvtXW<<<dim3(NNODES + 1024, 2), 256, 0, stream>>>(pro1_x, pro2_x, dinv, xs, W_g1, W_g2, Wtb);
  k_gather<<<dim3(NPAD, 2), 128, 0, stream>>>(xs, rowstart, csr, dinv, xa);
  k_gemm<<<dim3(79, 8, 2), 256, 0, stream>>>(xa, Wtb, b_g1, b_g2, hh);
  k_pool<<<dim3(FDIM/256, BGR, 2), 256, 0, stream>>>(hh, bstart, pool);
  k_pf<<<dim3(BGR, 2), 512, 0, stream>>>(pool, W_pf1, W_pf2, b_pf1, b_pf2, x12);
  k_masif<<<dim3(BGR, 2), 256, 0, stream>>>(mas1_s, mas1_f, mas2_s, mas2_f,
                                            cs1w, cs1b, cf1w, cf1b,
                                            cs2w, cs2b, cf2w, cf2b,
                                            W_m1, b_m1, W_m2, b_m2, m12);
  k_head<<<BGR, 256, 0, stream>>>(x12, W_fc1, b_fc1, W_fc2, b_fc2, m12, W_out, b_out, out);
}

// Round 10
// 241.538 us; speedup vs baseline: 1.0251x; 1.0251x over previous
//
#include <hip/hip_runtime.h>
#include <hip/hip_bf16.h>
#include <math.h>

#define NNODES 10000
#define NEDGES 80000
#define FDIM   1024
#define BGR    32
#define LLEN   800
#define CCH    16
#define DDIM   128
#define NPAD   10112   // 79 * 128
#define NE_BLK 625     // 2*NEDGES/256

typedef __attribute__((ext_vector_type(4))) _Float16 f16x4;
typedef __attribute__((ext_vector_type(8))) _Float16 f16x8;
typedef __attribute__((ext_vector_type(4))) float f32x4;

__device__ __forceinline__ float lrelu(float v){ return v > 0.0f ? v : 0.01f*v; }

// ---------------- device bodies ----------------

// GEMM body: R7 2-buffer counted-vmcnt schedule + XCD-local bijection over 632 blocks.
__device__ __forceinline__ void gemm_body(int id, int br,
    const _Float16* __restrict__ A_, const _Float16* __restrict__ Bt_,
    const float* __restrict__ bg0, const float* __restrict__ bg1,
    _Float16* __restrict__ hh_)
{
  __shared__ _Float16 As[2][128*32];
  __shared__ _Float16 Bs[2][128*32];
  const int w   = (id & 7)*79 + (id >> 3);   // XCD-local bijection (632 = 8*79)
  const int col = w & 7;
  const int row = w >> 3;

  const _Float16* A  = A_  + (size_t)br*NPAD*FDIM;
  const _Float16* Bt = Bt_ + (size_t)br*FDIM*FDIM;
  const float* bg = br ? bg1 : bg0;
  _Float16* hh = hh_ + (size_t)br*NPAD*FDIM;

  const int row0 = row*128, col0 = col*128;
  const int tid  = threadIdx.x;
  const int lane = tid & 63, wave = tid >> 6;
  const int wm = wave >> 1, wn = wave & 1;
  const int lr = lane >> 2;
  const int ls = lane & 3;

  f32x4 acc[4][4] = {};

  auto stage = [&](int buf, int k0){
    #pragma unroll
    for (int j = 0; j < 2; ++j){
      const int r0 = wave*32 + j*16;
      const int ra = r0 + lr;
      const int sa = ls ^ ((ra >> 1) & 3);
      __builtin_amdgcn_global_load_lds(
        (const __attribute__((address_space(1))) void*)(A + (size_t)(row0+ra)*FDIM + k0 + sa*8),
        (__attribute__((address_space(3))) void*)(&As[buf][r0*32]), 16, 0, 0);
      __builtin_amdgcn_global_load_lds(
        (const __attribute__((address_space(1))) void*)(Bt + (size_t)(col0+ra)*FDIM + k0 + sa*8),
        (__attribute__((address_space(3))) void*)(&Bs[buf][r0*32]), 16, 0, 0);
    }
  };

  auto compute = [&](int buf){
    f16x8 af[4], bf[4];
    const int s = lane >> 4;
    #pragma unroll
    for (int i = 0; i < 4; ++i){
      const int rA = wm*64 + i*16 + (lane&15);
      af[i] = *(const f16x8*)(&As[buf][rA*32 + (s ^ ((rA>>1)&3))*8]);
      const int rB = wn*64 + i*16 + (lane&15);
      bf[i] = *(const f16x8*)(&Bs[buf][rB*32 + (s ^ ((rB>>1)&3))*8]);
    }
    #pragma unroll
    for (int mi = 0; mi < 4; ++mi)
      #pragma unroll
      for (int ni = 0; ni < 4; ++ni)
        acc[mi][ni] = __builtin_amdgcn_mfma_f32_16x16x32_f16(af[mi], bf[ni], acc[mi][ni], 0, 0, 0);
  };

  stage(0, 0);
  #pragma unroll 2
  for (int ks = 0; ks < 32; ++ks){
    if (ks < 31){
      stage((ks+1)&1, (ks+1)*32);
      asm volatile("s_waitcnt vmcnt(4)" ::: "memory");
    } else {
      asm volatile("s_waitcnt vmcnt(0)" ::: "memory");
    }
    __builtin_amdgcn_s_barrier();
    compute(ks&1);
    __builtin_amdgcn_s_barrier();
  }

  float bcol[4];
  #pragma unroll
  for (int ni = 0; ni < 4; ++ni) bcol[ni] = bg[col0 + wn*64 + ni*16 + (lane & 15)];
  #pragma unroll
  for (int mi = 0; mi < 4; ++mi){
    #pragma unroll
    for (int j = 0; j < 4; ++j){
      const int grow = row0 + wm*64 + mi*16 + (lane>>4)*4 + j;
      _Float16* hr = hh + (size_t)grow*FDIM + col0 + wn*64 + (lane & 15);
      #pragma unroll
      for (int ni = 0; ni < 4; ++ni) hr[ni*16] = (_Float16)lrelu(acc[mi][ni][j] + bcol[ni]);
    }
  }
}

// gather one node: lt in [0,128), f = lt*8
__device__ __forceinline__ void gather_body(int n, int br, int lt,
    const _Float16* __restrict__ xs_, const int* __restrict__ rowstart_,
    const int* __restrict__ csr_, const float* __restrict__ dinv_,
    _Float16* __restrict__ xa_)
{
  const _Float16* xs = xs_ + (size_t)br*NNODES*FDIM;
  const int* rowstart = rowstart_ + br*(NNODES+1);
  const int* csr = csr_ + br*NEDGES;
  const float* dinv = dinv_ + br*NNODES;
  _Float16* xa = xa_ + (size_t)br*NPAD*FDIM;

  const int f = lt*8;
  _Float16* op = xa + (size_t)n*FDIM + f;
  if (n >= NNODES){
    f16x8 z = {};
    *(f16x8*)op = z;
    return;
  }
  const int s0 = rowstart[n], s1 = rowstart[n+1];
  f16x8 sv = *(const f16x8*)(xs + (size_t)n*FDIM + f);
  float a0=sv[0],a1=sv[1],a2=sv[2],a3=sv[3],a4=sv[4],a5=sv[5],a6=sv[6],a7=sv[7];
  int i = s0;
  for (; i + 4 <= s1; i += 4){
    const int r0 = csr[i], r1 = csr[i+1], r2 = csr[i+2], r3 = csr[i+3];
    f16x8 v0 = *(const f16x8*)(xs + (size_t)r0*FDIM + f);
    f16x8 v1 = *(const f16x8*)(xs + (size_t)r1*FDIM + f);
    f16x8 v2 = *(const f16x8*)(xs + (size_t)r2*FDIM + f);
    f16x8 v3 = *(const f16x8*)(xs + (size_t)r3*FDIM + f);
    a0 += (float)v0[0]+(float)v1[0]+(float)v2[0]+(float)v3[0];
    a1 += (float)v0[1]+(float)v1[1]+(float)v2[1]+(float)v3[1];
    a2 += (float)v0[2]+(float)v1[2]+(float)v2[2]+(float)v3[2];
    a3 += (float)v0[3]+(float)v1[3]+(float)v2[3]+(float)v3[3];
    a4 += (float)v0[4]+(float)v1[4]+(float)v2[4]+(float)v3[4];
    a5 += (float)v0[5]+(float)v1[5]+(float)v2[5]+(float)v3[5];
    a6 += (float)v0[6]+(float)v1[6]+(float)v2[6]+(float)v3[6];
    a7 += (float)v0[7]+(float)v1[7]+(float)v2[7]+(float)v3[7];
  }
  for (; i < s1; ++i){
    const int r = csr[i];
    f16x8 v = *(const f16x8*)(xs + (size_t)r*FDIM + f);
    a0+=(float)v[0]; a1+=(float)v[1]; a2+=(float)v[2]; a3+=(float)v[3];
    a4+=(float)v[4]; a5+=(float)v[5]; a6+=(float)v[6]; a7+=(float)v[7];
  }
  const float d = dinv[n];
  f16x8 o;
  o[0]=(_Float16)(a0*d); o[1]=(_Float16)(a1*d); o[2]=(_Float16)(a2*d); o[3]=(_Float16)(a3*d);
  o[4]=(_Float16)(a4*d); o[5]=(_Float16)(a5*d); o[6]=(_Float16)(a6*d); o[7]=(_Float16)(a7*d);
  *(f16x8*)op = o;
}

// pool one (pb) unit: pb in [0,128): col-chunk = pb&3, batch = pb>>2
__device__ __forceinline__ void pool_body(int pb, int br, int t,
    const _Float16* __restrict__ hh_, const int* __restrict__ bstart_,
    float* __restrict__ pool_)
{
  const _Float16* hh = hh_ + (size_t)br*NPAD*FDIM;
  const int* bstart = bstart_ + br*(BGR+1);
  float* pool = pool_ + br*BGR*FDIM;
  const int b = pb >> 2;
  const int col = (pb & 3)*256 + t;
  const int s0 = bstart[b], s1 = bstart[b+1];
  float sum = 0.f;
  int n = s0;
  for (; n + 4 <= s1; n += 4){
    float h0 = (float)hh[(size_t)(n  )*FDIM + col];
    float h1 = (float)hh[(size_t)(n+1)*FDIM + col];
    float h2 = (float)hh[(size_t)(n+2)*FDIM + col];
    float h3 = (float)hh[(size_t)(n+3)*FDIM + col];
    sum += (h0+h1)+(h2+h3);
  }
  for (; n < s1; ++n) sum += (float)hh[(size_t)n*FDIM + col];
  const float inv = 1.0f / fmaxf((float)(s1 - s0), 1.0f);
  pool[b*FDIM + col] = sum * inv;
}

// ---------------- kernels ----------------

// misc1: edgedeg (both) || W transpose+cast (both) || masif (both). grid 2737, blk 256
__global__ __launch_bounds__(256) void k_misc1(const int* __restrict__ ei0, const int* __restrict__ ei1,
                                               int* __restrict__ cnt,
                                               const float* __restrict__ W0, const float* __restrict__ W1,
                                               _Float16* __restrict__ Wt,
                                               const float* __restrict__ ms1, const float* __restrict__ mf1,
                                               const float* __restrict__ ms2, const float* __restrict__ mf2,
                                               const float* __restrict__ sw1, const float* __restrict__ sb1,
                                               const float* __restrict__ fw1, const float* __restrict__ fb1,
                                               const float* __restrict__ sw2, const float* __restrict__ sb2,
                                               const float* __restrict__ fw2, const float* __restrict__ fb2,
                                               const float* __restrict__ Wm1, const float* __restrict__ bm1,
                                               const float* __restrict__ Wm2, const float* __restrict__ bm2,
                                               float* __restrict__ m12){
  __shared__ float tl[32][33];
  __shared__ float sf[LLEN];
  __shared__ float w80[80];
  const int bx = blockIdx.x, t = threadIdx.x;
  if (bx < NE_BLK){
    int i = bx*256 + t;
    int br = i >= NEDGES;
    int e  = br ? i - NEDGES : i;
    const int* ei = br ? ei1 : ei0;
    atomicAdd(&cnt[br*NNODES + ei[NEDGES + e]], 1);
  } else if (bx < NE_BLK + 2048){
    const int idx = bx - NE_BLK;
    const int br = idx >> 10, tile = idx & 1023;
    const float* W = br ? W1 : W0;
    _Float16* Wo = Wt + (size_t)br*FDIM*FDIM;
    const int k0 = (tile >> 5)*32, n0 = (tile & 31)*32;
    const int r = t >> 3, c4 = (t & 7)*4;
    const float4 v = *(const float4*)(W + (size_t)(k0+r)*FDIM + n0 + c4);
    tl[r][c4] = v.x; tl[r][c4+1] = v.y; tl[r][c4+2] = v.z; tl[r][c4+3] = v.w;
    __syncthreads();
    f16x4 o;
    o[0]=(_Float16)tl[c4  ][r];
    o[1]=(_Float16)tl[c4+1][r];
    o[2]=(_Float16)tl[c4+2][r];
    o[3]=(_Float16)tl[c4+3][r];
    *(f16x4*)(Wo + (size_t)(n0+r)*FDIM + k0 + c4) = o;
  } else {
    const int idx = bx - NE_BLK - 2048;   // 0..63
    const int br = idx >> 5, b = idx & 31;
    const float* ms = br ? ms2 : ms1;
    const float* mf = br ? mf2 : mf1;
    const float swv = (br ? sw2 : sw1)[0], sbv = (br ? sb2 : sb1)[0];
    const float fwv = (br ? fw2 : fw1)[0], fbv = (br ? fb2 : fb1)[0];
    const float* Wm = br ? Wm2 : Wm1;
    const float* bm = br ? bm2 : bm1;
    for (int l = t; l < LLEN; l += 256){
      float sm = 0.f, fm = 0.f;
      for (int c = 0; c < CCH; ++c){
        sm += ms[((size_t)b*CCH + c)*LLEN + l];
        fm += mf[((size_t)b*CCH + c)*LLEN + l];
      }
      sm = fmaxf(sm*(1.0f/16.0f)*swv + sbv, 0.f);
      fm = fmaxf(fm*(1.0f/16.0f)*fwv + fbv, 0.f);
      sf[l] = sm + fm;
    }
    __syncthreads();
    if (t < 80){
      float a = 0.f;
      for (int j = 0; j < 10; ++j) a += sf[t*10 + j];
      w80[t] = a * 0.05f;
    }
    __syncthreads();
    if (t < 64){
      float acc = bm[t];
      for (int k = 0; k < 80; ++k) acc += w80[k] * Wm[k*64 + t];
      m12[((size_t)br*BGR + b)*64 + t] = acc;
    }
  }
}

// per-branch exclusive scan + dinv + bstart; grid=2 blocks of 1024
__global__ __launch_bounds__(1024) void k_scan(const int* __restrict__ cnt, int* __restrict__ rowstart,
                                               float* __restrict__ dinv,
                                               const int* __restrict__ batch0,
                                               const int* __restrict__ batch1,
                                               int* __restrict__ bstart_){
  __shared__ int part[1024];
  const int br = blockIdx.x;
  const int* c = cnt + br*NNODES;
  int* rs = rowstart + br*(NNODES+1);
  float* dv = dinv + br*NNODES;
  const int* batch = br ? batch1 : batch0;
  int* bstart = bstart_ + br*(BGR+1);
  const int t = threadIdx.x;
  const int base = t*10;
  int local[10];
  int s = 0;
  #pragma unroll
  for (int i = 0; i < 10; ++i){
    int v = (base+i < NNODES) ? c[base+i] : 0;
    local[i] = s; s += v;
    if (base+i < NNODES) dv[base+i] = rsqrtf((float)v + 1.0f);
  }
  part[t] = s;
  __syncthreads();
  for (int off = 1; off < 1024; off <<= 1){
    int v = (t >= off) ? part[t-off] : 0;
    __syncthreads();
    part[t] += v;
    __syncthreads();
  }
  const int prev = (t == 0) ? 0 : part[t-1];
  #pragma unroll
  for (int i = 0; i < 10; ++i)
    if (base+i < NNODES) rs[base+i] = prev + local[i];
  if (t == 0) rs[NNODES] = NEDGES;
  for (int i = base; i < base+10 && i < NNODES; ++i){
    int b = batch[i];
    if (i == 0){ for (int bb = 0; bb <= b; ++bb) bstart[bb] = 0; }
    else {
      int pb = batch[i-1];
      if (b != pb) for (int bb = pb+1; bb <= b; ++bb) bstart[bb] = i;
    }
    if (i == NNODES-1){ for (int bb = b+1; bb <= BGR; ++bb) bstart[bb] = NNODES; }
  }
}

// misc2: CSR fill (both) || cvtX (both). grid 625+20000, blk 256
__global__ __launch_bounds__(256) void k_misc2(const int* __restrict__ ei0, const int* __restrict__ ei1,
                                               const int* __restrict__ rowstart,
                                               int* __restrict__ cursor, int* __restrict__ csr,
                                               const float* __restrict__ x0, const float* __restrict__ x1,
                                               const float* __restrict__ dinv,
                                               _Float16* __restrict__ xs){
  const int bx = blockIdx.x, t = threadIdx.x;
  if (bx < NE_BLK){
    int i = bx*256 + t;
    int br = i >= NEDGES;
    int e  = br ? i - NEDGES : i;
    const int* ei = br ? ei1 : ei0;
    int r = ei[e], c = ei[NEDGES + e];
    int pos = atomicAdd(&cursor[br*NNODES + c], 1);
    csr[br*NEDGES + rowstart[br*(NNODES+1) + c] + pos] = r;
  } else {
    const int idx = bx - NE_BLK;              // 0..19999
    const int br = idx >= NNODES;
    const int row = br ? idx - NNODES : idx;
    const float* x = (br ? x1 : x0) + (size_t)row*FDIM;
    _Float16* o = xs + ((size_t)br*NNODES + row)*FDIM;
    const int f = t*4;
    const float d = dinv[br*NNODES + row];
    const float4 v = *(const float4*)(x + f);
    f16x4 ov;
    ov[0]=(_Float16)(v.x*d); ov[1]=(_Float16)(v.y*d); ov[2]=(_Float16)(v.z*d); ov[3]=(_Float16)(v.w*d);
    *(f16x4*)(o + f) = ov;
  }
}

// gather one branch: grid 5056 (2 nodes/block), blk 256
__global__ __launch_bounds__(256) void k_gath(const _Float16* __restrict__ xs,
                                              const int* __restrict__ rowstart,
                                              const int* __restrict__ csr,
                                              const float* __restrict__ dinv,
                                              _Float16* __restrict__ xa, int br){
  const int t = threadIdx.x;
  const int n = blockIdx.x*2 + (t >> 7);
  gather_body(n, br, t & 127, xs, rowstart, csr, dinv, xa);
}

// gemm(br0) || gather(br1): grid 632 + 5056, blk 256
__global__ __launch_bounds__(256) void k_gg(const _Float16* __restrict__ xa,
                                            const _Float16* __restrict__ Wtb,
                                            const float* __restrict__ bg0, const float* __restrict__ bg1,
                                            _Float16* __restrict__ hh,
                                            const _Float16* __restrict__ xs,
                                            const int* __restrict__ rowstart,
                                            const int* __restrict__ csr,
                                            const float* __restrict__ dinv){
  const int bx = blockIdx.x, t = threadIdx.x;
  if (bx < 632){
    gemm_body(bx, 0, xa, Wtb, bg0, bg1, hh);
  } else {
    const int n = (bx - 632)*2 + (t >> 7);
    gather_body(n, 1, t & 127, xs, rowstart, csr, dinv, (_Float16*)xa);
  }
}

// gemm(br1) || pool(br0): grid 632 + 128, blk 256
__global__ __launch_bounds__(256) void k_gp(const _Float16* __restrict__ xa,
                                            const _Float16* __restrict__ Wtb,
                                            const float* __restrict__ bg0, const float* __restrict__ bg1,
                                            _Float16* __restrict__ hh,
                                            const int* __restrict__ bstart,
                                            float* __restrict__ pool){
  const int bx = blockIdx.x, t = threadIdx.x;
  if (bx < 632){
    gemm_body(bx, 1, xa, Wtb, bg0, bg1, hh);
  } else {
    pool_body(bx - 632, 0, t, hh, bstart, pool);
  }
}

// pool(br1): grid 128, blk 256
__global__ __launch_bounds__(256) void k_pool1(const _Float16* __restrict__ hh,
                                               const int* __restrict__ bstart,
                                               float* __restrict__ pool){
  pool_body(blockIdx.x, 1, threadIdx.x, hh, bstart, pool);
}

// fused pf GEMV; grid (32,2), blk 512
__global__ __launch_bounds__(512) void k_pf(const float* __restrict__ pool_,
                                            const float* __restrict__ W0,
                                            const float* __restrict__ W1,
                                            const float* __restrict__ bias0,
                                            const float* __restrict__ bias1,
                                            float* __restrict__ x12){
  __shared__ float red[512];
  const int br = blockIdx.y, b = blockIdx.x, t = threadIdx.x;
  const int d = t & 127, kq = t >> 7;
  const float* W = (br ? W1 : W0) + (size_t)kq*256*DDIM + d;
  const float* pp = pool_ + (size_t)(br*BGR + b)*FDIM + kq*256;
  float acc = 0.f;
  #pragma unroll 4
  for (int kk = 0; kk < 256; kk += 4){
    const float4 pv = *(const float4*)(pp + kk);
    acc += pv.x * W[(kk  )*DDIM] + pv.y * W[(kk+1)*DDIM]
         + pv.z * W[(kk+2)*DDIM] + pv.w * W[(kk+3)*DDIM];
  }
  red[t] = acc;
  __syncthreads();
  if (t < 128){
    float a = red[t] + red[t+128] + red[t+256] + red[t+384] + (br ? bias1 : bias0)[t];
    x12[((size_t)br*BGR + b)*DDIM + t] = lrelu(a);
  }
}

// head: fc1 -> fc2 -> final sigmoid; grid 32, blk 256
__global__ __launch_bounds__(256) void k_head(const float* __restrict__ x12,
                                              const float* __restrict__ Wfc1, const float* __restrict__ bfc1,
                                              const float* __restrict__ Wfc2, const float* __restrict__ bfc2,
                                              const float* __restrict__ m12,
                                              const float* __restrict__ Wout, const float* __restrict__ bout,
                                              float* __restrict__ out){
  __shared__ float xf[256];
  __shared__ float xc[64];
  __shared__ float red[192];
  const int b = blockIdx.x, t = threadIdx.x;
  const float* xin1 = x12 + (size_t)b*DDIM;
  const float* xin2 = x12 + (size_t)(BGR + b)*DDIM;
  float acc = bfc1[t];
  for (int k = 0; k < 128; ++k) acc += xin1[k] * Wfc1[k*256 + t];
  for (int k = 0; k < 128; ++k) acc += xin2[k] * Wfc1[(128+k)*256 + t];
  xf[t] = lrelu(acc);
  __syncthreads();
  if (t < 64){
    float a = bfc2[t];
    for (int k = 0; k < 256; ++k) a += xf[k] * Wfc2[k*64 + t];
    xc[t] = lrelu(a);
  }
  __syncthreads();
  if (t < 192){
    float v;
    if (t < 64)       v = xc[t] * Wout[t];
    else if (t < 128) v = m12[(size_t)b*64 + (t-64)] * Wout[t];
    else              v = m12[(size_t)(BGR + b)*64 + (t-128)] * Wout[t];
    red[t] = v;
  }
  __syncthreads();
  if (t == 0){
    float a = bout[0];
    for (int i = 0; i < 192; ++i) a += red[i];
    out[b] = 1.0f / (1.0f + expf(-a));
  }
}

extern "C" void kernel_launch(void* const* d_in, const int* in_sizes, int n_in,
                              void* d_out, int out_size, void* d_ws, size_t ws_size,
                              hipStream_t stream){
  const float* pro1_x = (const float*)d_in[0];
  const int*   ei1    = (const int*)d_in[1];
  const int*   batch1 = (const int*)d_in[2];
  const float* pro2_x = (const float*)d_in[3];
  const int*   ei2    = (const int*)d_in[4];
  const int*   batch2 = (const int*)d_in[5];
  const float* mas1_s = (const float*)d_in[6];
  const float* mas1_f = (const float*)d_in[7];
  const float* mas2_s = (const float*)d_in[8];
  const float* mas2_f = (const float*)d_in[9];
  const float* W_g1 = (const float*)d_in[10]; const float* b_g1 = (const float*)d_in[11];
  const float* W_g2 = (const float*)d_in[12]; const float* b_g2 = (const float*)d_in[13];
  const float* W_pf1= (const float*)d_in[14]; const float* b_pf1= (const float*)d_in[15];
  const float* W_pf2= (const float*)d_in[16]; const float* b_pf2= (const float*)d_in[17];
  const float* W_fc1= (const float*)d_in[18]; const float* b_fc1= (const float*)d_in[19];
  const float* W_fc2= (const float*)d_in[20]; const float* b_fc2= (const float*)d_in[21];
  const float* cs1w = (const float*)d_in[22]; const float* cs1b = (const float*)d_in[23];
  const float* cf1w = (const float*)d_in[24]; const float* cf1b = (const float*)d_in[25];
  const float* cs2w = (const float*)d_in[26]; const float* cs2b = (const float*)d_in[27];
  const float* cf2w = (const float*)d_in[28]; const float* cf2b = (const float*)d_in[29];
  const float* W_m1 = (const float*)d_in[30]; const float* b_m1 = (const float*)d_in[31];
  const float* W_m2 = (const float*)d_in[32]; const float* b_m2 = (const float*)d_in[33];
  const float* W_out= (const float*)d_in[34]; const float* b_out= (const float*)d_in[35];
  float* out = (float*)d_out;
  (void)in_sizes; (void)n_in; (void)out_size; (void)ws_size;

  char* p = (char*)d_ws;
  auto alloc = [&](size_t bytes)->char*{ char* r = p; p += (bytes + 255) & ~(size_t)255; return r; };
  _Float16* xs  = (_Float16*)alloc((size_t)2*NNODES*FDIM*2);
  _Float16* xa  = (_Float16*)alloc((size_t)2*NPAD*FDIM*2);
  _Float16* Wtb = (_Float16*)alloc((size_t)2*FDIM*FDIM*2);
  _Float16* hh  = (_Float16*)alloc((size_t)2*NPAD*FDIM*2);
  float* dinv = (float*)alloc((size_t)2*NNODES*4);
  int*   cntcur = (int*)alloc((size_t)4*NNODES*4);   // cnt then cursor, contiguous
  int*   cnt    = cntcur;
  int*   cursor = cntcur + 2*NNODES;
  int*   rowstart = (int*)alloc((size_t)2*(NNODES+1)*4);
  int*   csr  = (int*)alloc((size_t)2*NEDGES*4);
  int*   bstart = (int*)alloc((size_t)2*(BGR+1)*4);
  float* pool = (float*)alloc((size_t)2*BGR*FDIM*4);
  float* x12  = (float*)alloc((size_t)2*BGR*DDIM*4);
  float* m12  = (float*)alloc((size_t)2*BGR*64*4);

  // L1: zero cnt+cursor (one DMA)
  hipMemsetAsync(cntcur, 0, (size_t)4*NNODES*4, stream);
  // L2: edgedeg || cvtW || masif
  k_misc1<<<NE_BLK + 2048 + 64, 256, 0, stream>>>(ei1, ei2, cnt, W_g1, W_g2, Wtb,
                                                  mas1_s, mas1_f, mas2_s, mas2_f,
                                                  cs1w, cs1b, cf1w, cf1b,
                                                  cs2w, cs2b, cf2w, cf2b,
                                                  W_m1, b_m1, W_m2, b_m2, m12);
  // L3: scan (+dinv, +bstart)
  k_scan<<<2, 1024, 0, stream>>>(cnt, rowstart, dinv, batch1, batch2, bstart);
  // L4: fill || cvtX
  k_misc2<<<NE_BLK + 2*NNODES, 256, 0, stream>>>(ei1, ei2, rowstart, cursor, csr,
                                                 pro1_x, pro2_x, dinv, xs);
  // L5: gather(br0)
  k_gath<<<NPAD/2, 256, 0, stream>>>(xs, rowstart, csr, dinv, xa, 0);
  // L6: gemm(br0) || gather(br1)
  k_gg<<<632 + NPAD/2, 256, 0, stream>>>(xa, Wtb, b_g1, b_g2, hh, xs, rowstart, csr, dinv);
  // L7: gemm(br1) || pool(br0)
  k_gp<<<632 + 128, 256, 0, stream>>>(xa, Wtb, b_g1, b_g2, hh, bstart, pool);
  // L8: pool(br1)
  k_pool1<<<128, 256, 0, stream>>>(hh, bstart, pool);
  // L9: pf (both)
  k_pf<<<dim3(BGR, 2), 512, 0, stream>>>(pool, W_pf1, W_pf2, b_pf1, b_pf2, x12);
  // L10: head
  k_head<<<BGR, 256, 0, stream>>>(x12, W_fc1, b_fc1, W_fc2, b_fc2, m12, W_out, b_out, out);
}